// Round 9
// baseline (179.179 us; speedup 1.0000x reference)
//
#include <hip/hip_runtime.h>
#include <cstdint>

// ---------------- problem constants ----------------
#define DD     256
#define HH     1024
#define NNSEQ  4096
#define KDIM   3840          // 15 * 256 (conv-as-GEMM K)
#define MT     64            // tokens per block
#define XROWS  78            // MT + 14 halo rows
#define XPITCH 264           // 256 + 8 pad (bf16 elems); row = 528 B
#define EPSLN  1e-5f

typedef unsigned short u16;
typedef __attribute__((ext_vector_type(8))) short short8;
typedef __attribute__((ext_vector_type(4))) float f32x4;

#define MFMA(a, b, c) __builtin_amdgcn_mfma_f32_16x16x32_bf16(a, b, c, 0, 0, 0)

__device__ __forceinline__ u16 f2bf(float f) {           // RNE fp32 -> bf16
  unsigned u = __float_as_uint(f);
  u += 0x7FFF + ((u >> 16) & 1);
  return (u16)(u >> 16);
}
__device__ __forceinline__ float bf2f(u16 s) { return __uint_as_float(((unsigned)s) << 16); }

// ======== prep: pack weights into MFMA B-fragment slabs (unchanged R8) ========
// slab: 32 K-rows x 256 N-cols fp32 -> 8192 bf16:
//   dst[fi*512 + l*8 + j] = W[k = s*32 + (l>>4)*8 + j][n = fi*16 + (l&15)]
__global__ __launch_bounds__(256) void k_prep(
    const float* __restrict__ wmix, const float* __restrict__ wff1,
    const float* __restrict__ wff2, u16* __restrict__ wpk,
    u16* __restrict__ w1pk, u16* __restrict__ w2pk)
{
  __shared__ float t[32][257];
  const int b = blockIdx.x, tid = threadIdx.x;

  u16* dst;
  if (b < 120) {                                   // conv: slab s = b
    dst = wpk + (size_t)b * 8192;
    for (int r = 0; r < 32; ++r)
      t[r][tid] = wmix[(size_t)(b * 32 + r) * 256 + tid];
  } else if (b < 152) {                            // FF1: u = c2*8+s
    const int u = b - 120, c2 = u >> 3, s = u & 7;
    dst = w1pk + (size_t)u * 8192;
    for (int r = 0; r < 32; ++r)
      t[r][tid] = wff1[(size_t)(s * 32 + r) * 1024 + c2 * 256 + tid];
  } else {                                         // FF2: u = c2*8+s
    const int u = b - 152, c2 = u >> 3, s = u & 7;
    dst = w2pk + (size_t)u * 8192;
    for (int r = 0; r < 32; ++r)
      t[r][tid] = wff2[(size_t)(c2 * 256 + s * 32 + r) * 256 + tid];
  }
  __syncthreads();

  const int l = tid & 63, q = l >> 4, cl = l & 15;
#pragma unroll
  for (int f = 0; f < 4; ++f) {
    const int fi = f * 4 + (tid >> 6);
    const int n = fi * 16 + cl;
    uint4 pk;
    unsigned* p = (unsigned*)&pk;
#pragma unroll
    for (int jj = 0; jj < 4; ++jj)
      p[jj] = (unsigned)f2bf(t[q * 8 + jj * 2][n]) | ((unsigned)f2bf(t[q * 8 + jj * 2 + 1][n]) << 16);
    *(uint4*)&dst[(size_t)fi * 512 + l * 8] = pk;
  }
}

// ===== kernel 1: causal conv, y = x + mix (bf16) =====
// grid 1024 = 256 m-tiles x 4 n-tiles. 256 thr = 4 waves = 4 K-GROUPS.
// Each wave: full 64x64 tile, K-quarter 960 (30 steps). A read ONCE per block.
// Epilogue: 3-slot LDS tree reduction of fp32 partials (3 barriers).
__global__ __launch_bounds__(256, 3) void k_conv(
    const float* __restrict__ x, const u16* __restrict__ wpk,
    const float* __restrict__ bmix, u16* __restrict__ yb)
{
  // union: xs (78*264 u16 = 41184 B) then 3 fp32 slots [64][65] (49920 B)
  __shared__ char smem[49920];
  u16* xs = (u16*)smem;

  const int tid = threadIdx.x;
  const int wv = tid >> 6, l = tid & 63, q = l >> 4, cl = l & 15;
  const int mtile = blockIdx.x >> 2, nb = blockIdx.x & 3;
  const long tok0 = (long)mtile * MT;
  const int n0 = (int)(tok0 & (NNSEQ - 1));

  // ---- stage x rows [tok0-14, tok0+63] as bf16 (all 256 cols) ----
  {
    const int cslot = (tid & 63) * 4;
    for (int r = tid >> 6; r < XROWS; r += 4) {
      const int nloc = n0 - 14 + r;
      float4 v = make_float4(0.f, 0.f, 0.f, 0.f);
      if (nloc >= 0) v = *(const float4*)&x[(tok0 - 14 + r) * DD + cslot];
      uint2 pk;
      pk.x = (unsigned)f2bf(v.x) | ((unsigned)f2bf(v.y) << 16);
      pk.y = (unsigned)f2bf(v.z) | ((unsigned)f2bf(v.w) << 16);
      *(uint2*)&xs[r * XPITCH + cslot] = pk;
    }
  }
  __syncthreads();

  // ---- K-loop: wave wv does K-steps [wv*30, wv*30+30) over full 64x64 tile ----
  f32x4 acc[4][4];
#pragma unroll
  for (int nt = 0; nt < 4; ++nt) {
    const float bm = (wv == 0) ? bmix[nb * 64 + nt * 16 + cl] : 0.f;  // bias once
#pragma unroll
    for (int mt = 0; mt < 4; ++mt) acc[mt][nt] = (f32x4){bm, bm, bm, bm};
  }

  const u16* bbase = wpk + (size_t)(wv * 30) * 8192 + (size_t)(nb * 4) * 512 + (size_t)l * 8;

#define LOAD_A(dst, s_)                                                         \
  {                                                                             \
    const int ks = wv * 30 + (s_);                                              \
    const int xrow = ks >> 3, c0 = (ks & 7) * 32;                               \
    _Pragma("unroll")                                                           \
    for (int mt = 0; mt < 4; ++mt)                                              \
      dst[mt] = *(const short8*)&xs[(xrow + mt * 16 + cl) * XPITCH + c0 + q * 8]; \
  }
#define LOAD_B(dst, s_)                                                         \
  {                                                                             \
    const u16* bp = bbase + (size_t)(s_) * 8192;                                \
    _Pragma("unroll")                                                           \
    for (int nt = 0; nt < 4; ++nt)                                              \
      dst[nt] = *(const short8*)(bp + nt * 512);                                \
  }

  {
    short8 af[2][4], bfr[2][4];
    LOAD_A(af[0], 0) LOAD_B(bfr[0], 0)
    LOAD_A(af[1], 1) LOAD_B(bfr[1], 1)

#pragma unroll 2
    for (int s = 0; s < 30; ++s) {
      const int cur = s & 1;
#pragma unroll
      for (int mt = 0; mt < 4; ++mt)
#pragma unroll
        for (int nt = 0; nt < 4; ++nt)
          acc[mt][nt] = MFMA(af[cur][mt], bfr[cur][nt], acc[mt][nt]);
      if (s + 2 < 30) {
        LOAD_A(af[cur], s + 2)
        LOAD_B(bfr[cur], s + 2)
      }
    }
  }
#undef LOAD_A
#undef LOAD_B

  // ---- tree reduction of 4 K-partials (xs dead -> 3 fp32 slots [64][65]) ----
  __syncthreads();
  float* fb = (float*)smem;
#define SLOT_W(si)                                                              \
  _Pragma("unroll")                                                             \
  for (int mt = 0; mt < 4; ++mt)                                                \
    _Pragma("unroll")                                                           \
    for (int nt = 0; nt < 4; ++nt)                                              \
      _Pragma("unroll")                                                         \
      for (int reg = 0; reg < 4; ++reg)                                         \
        fb[(si) * 4160 + (mt * 16 + q * 4 + reg) * 65 + nt * 16 + cl] = acc[mt][nt][reg];
#define SLOT_R(si)                                                              \
  _Pragma("unroll")                                                             \
  for (int mt = 0; mt < 4; ++mt)                                                \
    _Pragma("unroll")                                                           \
    for (int nt = 0; nt < 4; ++nt)                                              \
      _Pragma("unroll")                                                         \
      for (int reg = 0; reg < 4; ++reg)                                         \
        acc[mt][nt][reg] += fb[(si) * 4160 + (mt * 16 + q * 4 + reg) * 65 + nt * 16 + cl];

  if (wv == 2) { SLOT_W(0) } else if (wv == 3) { SLOT_W(1) }
  __syncthreads();
  if (wv == 0) { SLOT_R(0) } else if (wv == 1) { SLOT_R(1) SLOT_W(2) }
  __syncthreads();
  if (wv == 0) {
    SLOT_R(2)
    // residual (fp32 x) + store yb
#pragma unroll
    for (int mt = 0; mt < 4; ++mt)
#pragma unroll
      for (int nt = 0; nt < 4; ++nt) {
        const int col = nb * 64 + nt * 16 + cl;
#pragma unroll
        for (int reg = 0; reg < 4; ++reg) {
          const int row = mt * 16 + q * 4 + reg;
          const float y = acc[mt][nt][reg] + x[(tok0 + row) * DD + col];
          yb[(tok0 + row) * DD + col] = f2bf(y);
        }
      }
  }
#undef SLOT_W
#undef SLOT_R
}

// ===== kernel 2: LN1 + FF1 + gelu + FF2 + residual + LN2 =====
// 256 blocks x 512 thr = 8 waves = 2 row-halves (mh) x 4 col-groups (ng).
// No K-splits: every output element owned by exactly one wave.
__global__ __launch_bounds__(512) void k_ffn(
    const u16* __restrict__ yb, const float* __restrict__ g1,
    const float* __restrict__ b1, const u16* __restrict__ w1pk,
    const float* __restrict__ bf1, const u16* __restrict__ w2pk,
    const float* __restrict__ bf2, const float* __restrict__ g2,
    const float* __restrict__ b2, float* __restrict__ out)
{
  __shared__ u16 hs[64 * XPITCH];                  // 33.8 KB: y, then h in place
  __shared__ u16 asb[64 * XPITCH];                 // 33.8 KB: gelu acts (256-col chunk)
  __shared__ float redS[4][64], redS2[4][64];
  __shared__ float muL[64], invL[64];

  const int tid = threadIdx.x;
  const int wv = tid >> 6, l = tid & 63, q = l >> 4, cl = l & 15;
  const int mh = wv >> 2, ng = wv & 3;
  const long tok0 = (long)blockIdx.x * MT;

  // ---- stage y (bf16 direct copy) ----
  {
    const int chunk = tid & 31;
#pragma unroll
    for (int i = 0; i < 4; ++i) {
      const int row = (tid >> 5) + i * 16;
      *(uint4*)&hs[row * XPITCH + chunk * 8] = *(const uint4*)&yb[(tok0 + row) * DD + chunk * 8];
    }
  }
  __syncthreads();

  // ---- LN1: 8 lanes per row, 32 cols each; h written in place ----
  {
    const int row = tid >> 3, seg = tid & 7;
    uint4 v[4];
#pragma unroll
    for (int i = 0; i < 4; ++i)
      v[i] = *(const uint4*)&hs[row * XPITCH + seg * 32 + i * 8];
    float yv[32];
#pragma unroll
    for (int i = 0; i < 4; ++i) {
      const unsigned* w = (const unsigned*)&v[i];
#pragma unroll
      for (int j = 0; j < 4; ++j) {
        yv[i * 8 + j * 2]     = __uint_as_float(w[j] << 16);
        yv[i * 8 + j * 2 + 1] = __uint_as_float(w[j] & 0xffff0000u);
      }
    }
    float s = 0.f, s2 = 0.f;
#pragma unroll
    for (int k = 0; k < 32; ++k) { s += yv[k]; s2 += yv[k] * yv[k]; }
#pragma unroll
    for (int off = 1; off < 8; off <<= 1) { s += __shfl_xor(s, off, 64); s2 += __shfl_xor(s2, off, 64); }
    const float mu  = s * (1.f / DD);
    const float var = s2 * (1.f / DD) - mu * mu;
    const float inv = rsqrtf(var + EPSLN);
#pragma unroll
    for (int i = 0; i < 4; ++i) {
      const float4 gv0 = *(const float4*)&g1[seg * 32 + i * 8];
      const float4 gv1 = *(const float4*)&g1[seg * 32 + i * 8 + 4];
      const float4 bv0 = *(const float4*)&b1[seg * 32 + i * 8];
      const float4 bv1 = *(const float4*)&b1[seg * 32 + i * 8 + 4];
      const float g[8] = {gv0.x, gv0.y, gv0.z, gv0.w, gv1.x, gv1.y, gv1.z, gv1.w};
      const float bb[8] = {bv0.x, bv0.y, bv0.z, bv0.w, bv1.x, bv1.y, bv1.z, bv1.w};
      uint4 pk;
      unsigned* p = (unsigned*)&pk;
#pragma unroll
      for (int j = 0; j < 4; ++j) {
        const float h0 = (yv[i * 8 + j * 2]     - mu) * inv * g[j * 2]     + bb[j * 2];
        const float h1 = (yv[i * 8 + j * 2 + 1] - mu) * inv * g[j * 2 + 1] + bb[j * 2 + 1];
        p[j] = (unsigned)f2bf(h0) | ((unsigned)f2bf(h1) << 16);
      }
      *(uint4*)&hs[row * XPITCH + seg * 32 + i * 8] = pk;
    }
  }
  __syncthreads();

  // ---- FFN: 4 chunks of 256 H-cols; wave tile 32 rows x 64 cols ----
  f32x4 acc2[2][4];
#pragma unroll
  for (int nt = 0; nt < 4; ++nt) {
    const float bv = bf2[ng * 64 + nt * 16 + cl];
#pragma unroll
    for (int mt = 0; mt < 2; ++mt) acc2[mt][nt] = (f32x4){bv, bv, bv, bv};
  }

  for (int c = 0; c < 4; ++c) {
    // FF1: rows [mh*32,+32) x chunk-cols [ng*64,+64), K = 256
    f32x4 acc1[2][4];
#pragma unroll
    for (int nt = 0; nt < 4; ++nt) {
      const float bv = bf1[c * 256 + ng * 64 + nt * 16 + cl];
#pragma unroll
      for (int mt = 0; mt < 2; ++mt) acc1[mt][nt] = (f32x4){bv, bv, bv, bv};
    }
#pragma unroll
    for (int s = 0; s < 8; ++s) {
      short8 a[2], b[4];
#pragma unroll
      for (int mt = 0; mt < 2; ++mt)
        a[mt] = *(const short8*)&hs[(mh * 32 + mt * 16 + cl) * XPITCH + s * 32 + q * 8];
      const u16* bp = w1pk + (size_t)(c * 8 + s) * 8192 + (size_t)(ng * 4) * 512 + (size_t)l * 8;
#pragma unroll
      for (int nt = 0; nt < 4; ++nt)
        b[nt] = *(const short8*)(bp + nt * 512);
#pragma unroll
      for (int mt = 0; mt < 2; ++mt)
#pragma unroll
        for (int nt = 0; nt < 4; ++nt)
          acc1[mt][nt] = MFMA(a[mt], b[nt], acc1[mt][nt]);
    }
    // exact gelu -> asb (A-layout, chunk-local cols)
#pragma unroll
    for (int mt = 0; mt < 2; ++mt)
#pragma unroll
      for (int nt = 0; nt < 4; ++nt)
#pragma unroll
        for (int reg = 0; reg < 4; ++reg) {
          const float v = acc1[mt][nt][reg];
          const float g = 0.5f * v * (1.f + erff(v * 0.70710678118654752f));
          asb[(mh * 32 + mt * 16 + q * 4 + reg) * XPITCH + ng * 64 + nt * 16 + cl] = f2bf(g);
        }
    __syncthreads();
    // FF2: rows [mh*32,+32) x out-cols [ng*64,+64), K = chunk's 256
#pragma unroll
    for (int s = 0; s < 8; ++s) {
      short8 a[2], b[4];
#pragma unroll
      for (int mt = 0; mt < 2; ++mt)
        a[mt] = *(const short8*)&asb[(mh * 32 + mt * 16 + cl) * XPITCH + s * 32 + q * 8];
      const u16* bp = w2pk + (size_t)(c * 8 + s) * 8192 + (size_t)(ng * 4) * 512 + (size_t)l * 8;
#pragma unroll
      for (int nt = 0; nt < 4; ++nt)
        b[nt] = *(const short8*)(bp + nt * 512);
#pragma unroll
      for (int mt = 0; mt < 2; ++mt)
#pragma unroll
        for (int nt = 0; nt < 4; ++nt)
          acc2[mt][nt] = MFMA(a[mt], b[nt], acc2[mt][nt]);
    }
    __syncthreads();                               // asb reused next chunk
  }

  // ---- residual (h bf16 from LDS) + LN2 partial sums ----
  {
    float ps[2][4], ps2[2][4];
#pragma unroll
    for (int mt = 0; mt < 2; ++mt)
#pragma unroll
      for (int reg = 0; reg < 4; ++reg) {
        const int row = mh * 32 + mt * 16 + q * 4 + reg;
        float s = 0.f, s2 = 0.f;
#pragma unroll
        for (int nt = 0; nt < 4; ++nt) {
          const int col = ng * 64 + nt * 16 + cl;
          const float y = acc2[mt][nt][reg] + bf2f(hs[row * XPITCH + col]);
          acc2[mt][nt][reg] = y;
          s += y; s2 += y * y;
        }
#pragma unroll
        for (int off = 1; off < 16; off <<= 1) { s += __shfl_xor(s, off, 64); s2 += __shfl_xor(s2, off, 64); }
        ps[mt][reg] = s; ps2[mt][reg] = s2;
      }
    if (cl == 0) {
#pragma unroll
      for (int mt = 0; mt < 2; ++mt)
#pragma unroll
        for (int reg = 0; reg < 4; ++reg) {
          const int row = mh * 32 + mt * 16 + q * 4 + reg;
          redS[ng][row] = ps[mt][reg]; redS2[ng][row] = ps2[mt][reg];
        }
    }
  }
  __syncthreads();
  if (tid < 64) {
    const float s  = redS[0][tid] + redS[1][tid] + redS[2][tid] + redS[3][tid];
    const float s2 = redS2[0][tid] + redS2[1][tid] + redS2[2][tid] + redS2[3][tid];
    const float mu = s * (1.f / DD);
    const float var = s2 * (1.f / DD) - mu * mu;
    muL[tid] = mu; invL[tid] = rsqrtf(var + EPSLN);
  }
  __syncthreads();

#pragma unroll
  for (int nt = 0; nt < 4; ++nt) {
    const int col = ng * 64 + nt * 16 + cl;
    const float gv = g2[col], bv = b2[col];
#pragma unroll
    for (int mt = 0; mt < 2; ++mt)
#pragma unroll
      for (int reg = 0; reg < 4; ++reg) {
        const int row = mh * 32 + mt * 16 + q * 4 + reg;
        out[(tok0 + row) * DD + col] = (acc2[mt][nt][reg] - muL[row]) * invL[row] * gv + bv;
      }
  }
}

// ---------------- launch ----------------
extern "C" void kernel_launch(void* const* d_in, const int* in_sizes, int n_in,
                              void* d_out, int out_size, void* d_ws, size_t ws_size,
                              hipStream_t stream) {
  const float* x    = (const float*)d_in[0];
  const float* wmix = (const float*)d_in[1];   // [3840][256]
  const float* bmix = (const float*)d_in[2];
  const float* g1   = (const float*)d_in[3];
  const float* b1   = (const float*)d_in[4];
  const float* wff1 = (const float*)d_in[5];   // [256][1024]
  const float* bff1 = (const float*)d_in[6];
  const float* wff2 = (const float*)d_in[7];   // [1024][256]
  const float* bff2 = (const float*)d_in[8];
  const float* g2   = (const float*)d_in[9];
  const float* b2   = (const float*)d_in[10];
  float* out = (float*)d_out;

  u16* wpk  = (u16*)d_ws;                // 120*8192 = 983040 elems (1.97 MB)
  u16* w1pk = wpk + 983040;              // 32*8192 = 262144
  u16* w2pk = w1pk + 262144;             // 262144
  u16* yb   = w2pk + 262144;             // 16384*256 bf16 (8 MB)

  k_prep<<<184, 256, 0, stream>>>(wmix, wff1, wff2, wpk, w1pk, w2pk);

  k_conv<<<1024, 256, 0, stream>>>(x, wpk, bmix, yb);
  k_ffn <<<256, 512, 0, stream>>>(yb, g1, b1, w1pk, bff1, w2pk, bff2, g2, b2, out);
}

// Round 10
// 160.252 us; speedup vs baseline: 1.1181x; 1.1181x over previous
//
#include <hip/hip_runtime.h>
#include <cstdint>

// ---------------- problem constants ----------------
#define DD     256
#define HH     1024
#define NNSEQ  4096
#define KDIM   3840          // 15 * 256 (conv-as-GEMM K)
#define MT     64            // tokens per block
#define XROWS  78            // MT + 14 halo rows
#define XPITCH 264           // 256 + 8 pad (bf16 elems)
#define SLOTP  260           // fp32 slot pitch
#define EPSLN  1e-5f

typedef unsigned short u16;
typedef __attribute__((ext_vector_type(8))) short short8;
typedef __attribute__((ext_vector_type(4))) float f32x4;

#define MFMA(a, b, c) __builtin_amdgcn_mfma_f32_16x16x32_bf16(a, b, c, 0, 0, 0)

__device__ __forceinline__ u16 f2bf(float f) {           // RNE fp32 -> bf16
  unsigned u = __float_as_uint(f);
  u += 0x7FFF + ((u >> 16) & 1);
  return (u16)(u >> 16);
}
__device__ __forceinline__ float bf2f(u16 s) { return __uint_as_float(((unsigned)s) << 16); }

// ======== prep: pack weights into MFMA B-fragment slabs (unchanged) ========
// slab: 32 K-rows x 256 N-cols fp32 -> 8192 bf16:
//   dst[fi*512 + l*8 + j] = W[k = s*32 + (l>>4)*8 + j][n = fi*16 + (l&15)]
__global__ __launch_bounds__(256) void k_prep(
    const float* __restrict__ wmix, const float* __restrict__ wff1,
    const float* __restrict__ wff2, u16* __restrict__ wpk,
    u16* __restrict__ w1pk, u16* __restrict__ w2pk)
{
  __shared__ float t[32][257];
  const int b = blockIdx.x, tid = threadIdx.x;

  u16* dst;
  if (b < 120) {                                   // conv: slab s = b
    dst = wpk + (size_t)b * 8192;
    for (int r = 0; r < 32; ++r)
      t[r][tid] = wmix[(size_t)(b * 32 + r) * 256 + tid];
  } else if (b < 152) {                            // FF1: u = c2*8+s
    const int u = b - 120, c2 = u >> 3, s = u & 7;
    dst = w1pk + (size_t)u * 8192;
    for (int r = 0; r < 32; ++r)
      t[r][tid] = wff1[(size_t)(s * 32 + r) * 1024 + c2 * 256 + tid];
  } else {                                         // FF2: u = c2*8+s
    const int u = b - 152, c2 = u >> 3, s = u & 7;
    dst = w2pk + (size_t)u * 8192;
    for (int r = 0; r < 32; ++r)
      t[r][tid] = wff2[(size_t)(c2 * 256 + s * 32 + r) * 256 + tid];
  }
  __syncthreads();

  const int l = tid & 63, q = l >> 4, cl = l & 15;
#pragma unroll
  for (int f = 0; f < 4; ++f) {
    const int fi = f * 4 + (tid >> 6);
    const int n = fi * 16 + cl;
    uint4 pk;
    unsigned* p = (unsigned*)&pk;
#pragma unroll
    for (int jj = 0; jj < 4; ++jj)
      p[jj] = (unsigned)f2bf(t[q * 8 + jj * 2][n]) | ((unsigned)f2bf(t[q * 8 + jj * 2 + 1][n]) << 16);
    *(uint4*)&dst[(size_t)fi * 512 + l * 8] = pk;
  }
}

// ===== fused: conv(mg K-split, B read once) + LN1 + FFN + LN2 =====
// grid 256 (1 block/CU), 512 thr = 8 waves = 2 K-halves (mg) x 4 col-groups (ng).
// Conv wave: ALL 64 rows x 64 cols x K-half 1920 (60 steps, depth-3 prefetch).
__global__ __launch_bounds__(512) void k_fused(
    const float* __restrict__ x, const u16* __restrict__ wpk,
    const float* __restrict__ bmix, const float* __restrict__ g1,
    const float* __restrict__ b1, const u16* __restrict__ w1pk,
    const float* __restrict__ bf1, const u16* __restrict__ w2pk,
    const float* __restrict__ bf2, const float* __restrict__ g2,
    const float* __restrict__ b2, float* __restrict__ out)
{
  __shared__ u16 bufA[XROWS * XPITCH];             // 41.2 KB: xs, then h
  __shared__ float bufB[64 * SLOTP];               // 66.6 KB: mg1 fp32 partials, then asb
  __shared__ float redS[4][64], redS2[4][64];
  __shared__ float muL[64], invL[64];

  const int tid = threadIdx.x;
  const int wv = tid >> 6, l = tid & 63, q = l >> 4, cl = l & 15;
  const int mg = wv >> 2, ng = wv & 3;
  const long tok0 = (long)blockIdx.x * MT;
  const int n0 = (int)(tok0 & (NNSEQ - 1));

  // ---- stage x rows [tok0-14, tok0+63] as bf16 ----
  {
    const int cslot = (tid & 63) * 4;
    for (int r = tid >> 6; r < XROWS; r += 8) {
      const int nloc = n0 - 14 + r;
      float4 v = make_float4(0.f, 0.f, 0.f, 0.f);
      if (nloc >= 0) v = *(const float4*)&x[(tok0 - 14 + r) * DD + cslot];
      uint2 pk;
      pk.x = (unsigned)f2bf(v.x) | ((unsigned)f2bf(v.y) << 16);
      pk.y = (unsigned)f2bf(v.z) | ((unsigned)f2bf(v.w) << 16);
      *(uint2*)&bufA[r * XPITCH + cslot] = pk;
    }
  }
  __syncthreads();

  // ================= conv GEMM: K-half mg, cols ng*64.., all 64 rows ========
  f32x4 acc[4][4];
#pragma unroll
  for (int nt = 0; nt < 4; ++nt) {
    const float bm = (mg == 0) ? bmix[ng * 64 + nt * 16 + cl] : 0.f;
#pragma unroll
    for (int mt = 0; mt < 4; ++mt) acc[mt][nt] = (f32x4){bm, bm, bm, bm};
  }

  const u16* bbase = wpk + (size_t)(mg * 60) * 8192 + (size_t)(ng * 4) * 512 + (size_t)l * 8;

#define LOAD_A(dst, s_)                                                         \
  {                                                                             \
    const int ks = mg * 60 + (s_);                                              \
    const int xrow = ks >> 3, c0 = (ks & 7) * 32;                               \
    _Pragma("unroll")                                                           \
    for (int mt = 0; mt < 4; ++mt)                                              \
      dst[mt] = *(const short8*)&bufA[(xrow + mt * 16 + cl) * XPITCH + c0 + q * 8]; \
  }
#define LOAD_B(dst, s_)                                                         \
  {                                                                             \
    const u16* bp = bbase + (size_t)(s_) * 8192;                                \
    _Pragma("unroll")                                                           \
    for (int nt = 0; nt < 4; ++nt)                                              \
      dst[nt] = *(const short8*)(bp + nt * 512);                                \
  }

  {
    short8 af[3][4], bfr[3][4];
    LOAD_A(af[0], 0) LOAD_B(bfr[0], 0)
    LOAD_A(af[1], 1) LOAD_B(bfr[1], 1)
    LOAD_A(af[2], 2) LOAD_B(bfr[2], 2)

#pragma unroll 3
    for (int s = 0; s < 60; ++s) {
      const int cur = s % 3;
#pragma unroll
      for (int mt = 0; mt < 4; ++mt)
#pragma unroll
        for (int nt = 0; nt < 4; ++nt)
          acc[mt][nt] = MFMA(af[cur][mt], bfr[cur][nt], acc[mt][nt]);
      if (s + 3 < 60) {
        LOAD_A(af[cur], s + 3)
        LOAD_B(bfr[cur], s + 3)
      }
    }
  }
#undef LOAD_A
#undef LOAD_B

  // ---- mg1 -> fp32 slot; mg0 combines + residual + LN1 ----
  __syncthreads();                                 // A-reads done (bufA semi-dead)
  if (mg == 1) {
#pragma unroll
    for (int mt = 0; mt < 4; ++mt)
#pragma unroll
      for (int nt = 0; nt < 4; ++nt)
#pragma unroll
        for (int reg = 0; reg < 4; ++reg)
          bufB[(mt * 16 + q * 4 + reg) * SLOTP + ng * 64 + nt * 16 + cl] = acc[mt][nt][reg];
  }
  __syncthreads();

  if (mg == 0) {
    float ps[4][4], ps2[4][4];
#pragma unroll
    for (int mt = 0; mt < 4; ++mt)
#pragma unroll
      for (int reg = 0; reg < 4; ++reg) {
        const int row = mt * 16 + q * 4 + reg;
        float s = 0.f, s2 = 0.f;
#pragma unroll
        for (int nt = 0; nt < 4; ++nt) {
          const int col = ng * 64 + nt * 16 + cl;
          const float y = acc[mt][nt][reg] + bufB[row * SLOTP + col]
                        + x[(tok0 + row) * DD + col];        // fp32 residual
          acc[mt][nt][reg] = y;
          s += y; s2 += y * y;
        }
#pragma unroll
        for (int off = 1; off < 16; off <<= 1) { s += __shfl_xor(s, off, 64); s2 += __shfl_xor(s2, off, 64); }
        ps[mt][reg] = s; ps2[mt][reg] = s2;
      }
    if (cl == 0) {
#pragma unroll
      for (int mt = 0; mt < 4; ++mt)
#pragma unroll
        for (int reg = 0; reg < 4; ++reg) {
          const int row = mt * 16 + q * 4 + reg;
          redS[ng][row] = ps[mt][reg]; redS2[ng][row] = ps2[mt][reg];
        }
    }
  }
  __syncthreads();
  if (tid < 64) {
    const float s  = redS[0][tid] + redS[1][tid] + redS[2][tid] + redS[3][tid];
    const float s2 = redS2[0][tid] + redS2[1][tid] + redS2[2][tid] + redS2[3][tid];
    const float mu = s * (1.f / DD);
    const float var = s2 * (1.f / DD) - mu * mu;
    muL[tid] = mu; invL[tid] = rsqrtf(var + EPSLN);
  }
  __syncthreads();

  // ---- h (bf16) -> bufA rows 0..63 ----
  if (mg == 0) {
#pragma unroll
    for (int nt = 0; nt < 4; ++nt) {
      const int col = ng * 64 + nt * 16 + cl;
      const float gv = g1[col], bv = b1[col];
#pragma unroll
      for (int mt = 0; mt < 4; ++mt)
#pragma unroll
        for (int reg = 0; reg < 4; ++reg) {
          const int row = mt * 16 + q * 4 + reg;
          const float hv = (acc[mt][nt][reg] - muL[row]) * invL[row] * gv + bv;
          bufA[row * XPITCH + col] = f2bf(hv);
        }
    }
  }
  __syncthreads();

  // ================= FFN: 4 chunks of 256 H-cols; wave tile 32 x 64 =========
  u16* asb = (u16*)bufB;                           // 33.8 KB inside 66.6
  f32x4 acc2[2][4];
#pragma unroll
  for (int nt = 0; nt < 4; ++nt) {
    const float bv = bf2[ng * 64 + nt * 16 + cl];
#pragma unroll
    for (int mt = 0; mt < 2; ++mt) acc2[mt][nt] = (f32x4){bv, bv, bv, bv};
  }

  for (int c = 0; c < 4; ++c) {
    f32x4 acc1[2][4];
#pragma unroll
    for (int nt = 0; nt < 4; ++nt) {
      const float bv = bf1[c * 256 + ng * 64 + nt * 16 + cl];
#pragma unroll
      for (int mt = 0; mt < 2; ++mt) acc1[mt][nt] = (f32x4){bv, bv, bv, bv};
    }
#pragma unroll
    for (int s = 0; s < 8; ++s) {                  // FF1, K=256
      short8 a[2], b[4];
#pragma unroll
      for (int mt = 0; mt < 2; ++mt)
        a[mt] = *(const short8*)&bufA[(mg * 32 + mt * 16 + cl) * XPITCH + s * 32 + q * 8];
      const u16* bp = w1pk + (size_t)(c * 8 + s) * 8192 + (size_t)(ng * 4) * 512 + (size_t)l * 8;
#pragma unroll
      for (int nt = 0; nt < 4; ++nt)
        b[nt] = *(const short8*)(bp + nt * 512);
#pragma unroll
      for (int mt = 0; mt < 2; ++mt)
#pragma unroll
        for (int nt = 0; nt < 4; ++nt)
          acc1[mt][nt] = MFMA(a[mt], b[nt], acc1[mt][nt]);
    }
    // exact gelu -> asb (A-layout, chunk-local cols)
#pragma unroll
    for (int mt = 0; mt < 2; ++mt)
#pragma unroll
      for (int nt = 0; nt < 4; ++nt)
#pragma unroll
        for (int reg = 0; reg < 4; ++reg) {
          const float v = acc1[mt][nt][reg];
          const float g = 0.5f * v * (1.f + erff(v * 0.70710678118654752f));
          asb[(mg * 32 + mt * 16 + q * 4 + reg) * XPITCH + ng * 64 + nt * 16 + cl] = f2bf(g);
        }
    __syncthreads();
#pragma unroll
    for (int s = 0; s < 8; ++s) {                  // FF2, chunk K=256
      short8 a[2], b[4];
#pragma unroll
      for (int mt = 0; mt < 2; ++mt)
        a[mt] = *(const short8*)&asb[(mg * 32 + mt * 16 + cl) * XPITCH + s * 32 + q * 8];
      const u16* bp = w2pk + (size_t)(c * 8 + s) * 8192 + (size_t)(ng * 4) * 512 + (size_t)l * 8;
#pragma unroll
      for (int nt = 0; nt < 4; ++nt)
        b[nt] = *(const short8*)(bp + nt * 512);
#pragma unroll
      for (int mt = 0; mt < 2; ++mt)
#pragma unroll
        for (int nt = 0; nt < 4; ++nt)
          acc2[mt][nt] = MFMA(a[mt], b[nt], acc2[mt][nt]);
    }
    __syncthreads();                               // asb reused next chunk
  }

  // ---- residual (h from bufA) + LN2 ----
  {
    float ps[2][4], ps2[2][4];
#pragma unroll
    for (int mt = 0; mt < 2; ++mt)
#pragma unroll
      for (int reg = 0; reg < 4; ++reg) {
        const int row = mg * 32 + mt * 16 + q * 4 + reg;
        float s = 0.f, s2 = 0.f;
#pragma unroll
        for (int nt = 0; nt < 4; ++nt) {
          const int col = ng * 64 + nt * 16 + cl;
          const float y = acc2[mt][nt][reg] + bf2f(bufA[row * XPITCH + col]);
          acc2[mt][nt][reg] = y;
          s += y; s2 += y * y;
        }
#pragma unroll
        for (int off = 1; off < 16; off <<= 1) { s += __shfl_xor(s, off, 64); s2 += __shfl_xor(s2, off, 64); }
        ps[mt][reg] = s; ps2[mt][reg] = s2;
      }
    if (cl == 0) {
#pragma unroll
      for (int mt = 0; mt < 2; ++mt)
#pragma unroll
        for (int reg = 0; reg < 4; ++reg) {
          const int row = mg * 32 + mt * 16 + q * 4 + reg;
          redS[ng][row] = ps[mt][reg]; redS2[ng][row] = ps2[mt][reg];
        }
    }
  }
  __syncthreads();
  if (tid < 64) {
    const float s  = redS[0][tid] + redS[1][tid] + redS[2][tid] + redS[3][tid];
    const float s2 = redS2[0][tid] + redS2[1][tid] + redS2[2][tid] + redS2[3][tid];
    const float mu = s * (1.f / DD);
    const float var = s2 * (1.f / DD) - mu * mu;
    muL[tid] = mu; invL[tid] = rsqrtf(var + EPSLN);
  }
  __syncthreads();

#pragma unroll
  for (int nt = 0; nt < 4; ++nt) {
    const int col = ng * 64 + nt * 16 + cl;
    const float gv = g2[col], bv = b2[col];
#pragma unroll
    for (int mt = 0; mt < 2; ++mt)
#pragma unroll
      for (int reg = 0; reg < 4; ++reg) {
        const int row = mg * 32 + mt * 16 + q * 4 + reg;
        out[(tok0 + row) * DD + col] = (acc2[mt][nt][reg] - muL[row]) * invL[row] * gv + bv;
      }
  }
}

// ---------------- launch ----------------
extern "C" void kernel_launch(void* const* d_in, const int* in_sizes, int n_in,
                              void* d_out, int out_size, void* d_ws, size_t ws_size,
                              hipStream_t stream) {
  const float* x    = (const float*)d_in[0];
  const float* wmix = (const float*)d_in[1];   // [3840][256]
  const float* bmix = (const float*)d_in[2];
  const float* g1   = (const float*)d_in[3];
  const float* b1   = (const float*)d_in[4];
  const float* wff1 = (const float*)d_in[5];   // [256][1024]
  const float* bff1 = (const float*)d_in[6];
  const float* wff2 = (const float*)d_in[7];   // [1024][256]
  const float* bff2 = (const float*)d_in[8];
  const float* g2   = (const float*)d_in[9];
  const float* b2   = (const float*)d_in[10];
  float* out = (float*)d_out;

  u16* wpk  = (u16*)d_ws;                // 120*8192 = 983040 elems (1.97 MB)
  u16* w1pk = wpk + 983040;              // 32*8192 = 262144
  u16* w2pk = w1pk + 262144;             // 262144

  k_prep<<<184, 256, 0, stream>>>(wmix, wff1, wff2, wpk, w1pk, w2pk);

  k_fused<<<256, 512, 0, stream>>>(x, wpk, bmix, g1, b1,
                                   w1pk, bff1, w2pk, bff2, g2, b2, out);
}

// Round 11
// 155.306 us; speedup vs baseline: 1.1537x; 1.0318x over previous
//
#include <hip/hip_runtime.h>
#include <cstdint>

// ---------------- problem constants ----------------
#define DD     256
#define HH     1024
#define NNSEQ  4096
#define MT     32            // tokens per block (grid 512 = 2 blocks/CU)
#define XR     46            // MT + 14 halo rows
#define XPITCH 264           // 256 + 8 pad (bf16 elems), row 528 B
#define SLOTP  260           // fp32 slot pitch
#define EPSLN  1e-5f

typedef unsigned short u16;
typedef __attribute__((ext_vector_type(8))) short short8;
typedef __attribute__((ext_vector_type(4))) float f32x4;

#define MFMA(a, b, c) __builtin_amdgcn_mfma_f32_16x16x32_bf16(a, b, c, 0, 0, 0)

__device__ __forceinline__ u16 f2bf(float f) {           // RNE fp32 -> bf16
  unsigned u = __float_as_uint(f);
  u += 0x7FFF + ((u >> 16) & 1);
  return (u16)(u >> 16);
}
__device__ __forceinline__ float bf2f(u16 s) { return __uint_as_float(((unsigned)s) << 16); }

// ======== prep: pack weights into MFMA B-fragment slabs (unchanged) ========
// slab: 32 K-rows x 256 N-cols fp32 -> 8192 bf16:
//   dst[fi*512 + l*8 + j] = W[k = s*32 + (l>>4)*8 + j][n = fi*16 + (l&15)]
__global__ __launch_bounds__(256) void k_prep(
    const float* __restrict__ wmix, const float* __restrict__ wff1,
    const float* __restrict__ wff2, u16* __restrict__ wpk,
    u16* __restrict__ w1pk, u16* __restrict__ w2pk)
{
  __shared__ float t[32][257];
  const int b = blockIdx.x, tid = threadIdx.x;

  u16* dst;
  if (b < 120) {                                   // conv: slab s = b
    dst = wpk + (size_t)b * 8192;
    for (int r = 0; r < 32; ++r)
      t[r][tid] = wmix[(size_t)(b * 32 + r) * 256 + tid];
  } else if (b < 152) {                            // FF1: u = c2*8+s
    const int u = b - 120, c2 = u >> 3, s = u & 7;
    dst = w1pk + (size_t)u * 8192;
    for (int r = 0; r < 32; ++r)
      t[r][tid] = wff1[(size_t)(s * 32 + r) * 1024 + c2 * 256 + tid];
  } else {                                         // FF2: u = c2*8+s
    const int u = b - 152, c2 = u >> 3, s = u & 7;
    dst = w2pk + (size_t)u * 8192;
    for (int r = 0; r < 32; ++r)
      t[r][tid] = wff2[(size_t)(c2 * 256 + s * 32 + r) * 256 + tid];
  }
  __syncthreads();

  const int l = tid & 63, q = l >> 4, cl = l & 15;
#pragma unroll
  for (int f = 0; f < 4; ++f) {
    const int fi = f * 4 + (tid >> 6);
    const int n = fi * 16 + cl;
    uint4 pk;
    unsigned* p = (unsigned*)&pk;
#pragma unroll
    for (int jj = 0; jj < 4; ++jj)
      p[jj] = (unsigned)f2bf(t[q * 8 + jj * 2][n]) | ((unsigned)f2bf(t[q * 8 + jj * 2 + 1][n]) << 16);
    *(uint4*)&dst[(size_t)fi * 512 + l * 8] = pk;
  }
}

// ===== fused: conv(mg K-split) + LN1 + FFN + LN2, MT=32, 2 blocks/CU =====
// grid 512, 512 thr = 8 waves = 2 K-halves (mg) x 4 col-groups (ng).
// Conv wave: 32 rows (mt=2) x 64 cols (nt=4) x K-half 1920 (60 steps).
// LDS ~60 KB total -> 2 co-resident blocks per CU (the R10 fix).
__global__ __launch_bounds__(512, 4) void k_fused(
    const float* __restrict__ x, const u16* __restrict__ wpk,
    const float* __restrict__ bmix, const float* __restrict__ g1,
    const float* __restrict__ b1, const u16* __restrict__ w1pk,
    const float* __restrict__ bf1, const u16* __restrict__ w2pk,
    const float* __restrict__ bf2, const float* __restrict__ g2,
    const float* __restrict__ b2, float* __restrict__ out)
{
  __shared__ u16 bufA[XR * XPITCH];                // 24.3 KB: xs, then h rows 0..31
  __shared__ float bufB[MT * SLOTP];               // 33.3 KB: conv fp32 slot; asb overlay
  __shared__ float redS[8][MT], redS2[8][MT];      // 2 KB
  __shared__ float muL[MT], invL[MT];

  const int tid = threadIdx.x;
  const int wv = tid >> 6, l = tid & 63, q = l >> 4, cl = l & 15;
  const int mg = wv >> 2, ng = wv & 3;
  const long tok0 = (long)blockIdx.x * MT;
  const int n0 = (int)(tok0 & (NNSEQ - 1));

  // ---- stage x rows [tok0-14, tok0+31] as bf16 ----
  {
    const int cslot = (tid & 63) * 4;
    for (int r = tid >> 6; r < XR; r += 8) {
      const int nloc = n0 - 14 + r;
      float4 v = make_float4(0.f, 0.f, 0.f, 0.f);
      if (nloc >= 0) v = *(const float4*)&x[(tok0 - 14 + r) * DD + cslot];
      uint2 pk;
      pk.x = (unsigned)f2bf(v.x) | ((unsigned)f2bf(v.y) << 16);
      pk.y = (unsigned)f2bf(v.z) | ((unsigned)f2bf(v.w) << 16);
      *(uint2*)&bufA[r * XPITCH + cslot] = pk;
    }
  }
  __syncthreads();

  // ================= conv GEMM: K-half mg, cols ng*64.., 32 rows ========
  f32x4 acc[2][4];
#pragma unroll
  for (int nt = 0; nt < 4; ++nt) {
    const float bm = (mg == 0) ? bmix[ng * 64 + nt * 16 + cl] : 0.f;
#pragma unroll
    for (int mt = 0; mt < 2; ++mt) acc[mt][nt] = (f32x4){bm, bm, bm, bm};
  }

  const u16* bbase = wpk + (size_t)(mg * 60) * 8192 + (size_t)(ng * 4) * 512 + (size_t)l * 8;

#define LOAD_A(dst, s_)                                                         \
  {                                                                             \
    const int ks = mg * 60 + (s_);                                              \
    const int xrow = ks >> 3, c0 = (ks & 7) * 32;                               \
    _Pragma("unroll")                                                           \
    for (int mt = 0; mt < 2; ++mt)                                              \
      dst[mt] = *(const short8*)&bufA[(xrow + mt * 16 + cl) * XPITCH + c0 + q * 8]; \
  }
#define LOAD_B(dst, s_)                                                         \
  {                                                                             \
    const u16* bp = bbase + (size_t)(s_) * 8192;                                \
    _Pragma("unroll")                                                           \
    for (int nt = 0; nt < 4; ++nt)                                              \
      dst[nt] = *(const short8*)(bp + nt * 512);                                \
  }

  {
    short8 af[2][2], bfr[2][4];
    LOAD_A(af[0], 0) LOAD_B(bfr[0], 0)
    LOAD_A(af[1], 1) LOAD_B(bfr[1], 1)

#pragma unroll 2
    for (int s = 0; s < 60; ++s) {
      const int cur = s & 1;
#pragma unroll
      for (int mt = 0; mt < 2; ++mt)
#pragma unroll
        for (int nt = 0; nt < 4; ++nt)
          acc[mt][nt] = MFMA(af[cur][mt], bfr[cur][nt], acc[mt][nt]);
      if (s + 2 < 60) {
        LOAD_A(af[cur], s + 2)
        LOAD_B(bfr[cur], s + 2)
      }
    }
  }
#undef LOAD_A
#undef LOAD_B

  // ---- mg1 -> fp32 slot; mg0 combines + residual + LN1 ----
  __syncthreads();
  if (mg == 1) {
#pragma unroll
    for (int mt = 0; mt < 2; ++mt)
#pragma unroll
      for (int nt = 0; nt < 4; ++nt)
#pragma unroll
        for (int reg = 0; reg < 4; ++reg)
          bufB[(mt * 16 + q * 4 + reg) * SLOTP + ng * 64 + nt * 16 + cl] = acc[mt][nt][reg];
  }
  __syncthreads();

  if (mg == 0) {
    float ps[2][4], ps2[2][4];
#pragma unroll
    for (int mt = 0; mt < 2; ++mt)
#pragma unroll
      for (int reg = 0; reg < 4; ++reg) {
        const int row = mt * 16 + q * 4 + reg;
        float s = 0.f, s2 = 0.f;
#pragma unroll
        for (int nt = 0; nt < 4; ++nt) {
          const int col = ng * 64 + nt * 16 + cl;
          const float y = acc[mt][nt][reg] + bufB[row * SLOTP + col]
                        + x[(tok0 + row) * DD + col];        // fp32 residual
          acc[mt][nt][reg] = y;
          s += y; s2 += y * y;
        }
#pragma unroll
        for (int off = 1; off < 16; off <<= 1) { s += __shfl_xor(s, off, 64); s2 += __shfl_xor(s2, off, 64); }
        ps[mt][reg] = s; ps2[mt][reg] = s2;
      }
    if (cl == 0) {
#pragma unroll
      for (int mt = 0; mt < 2; ++mt)
#pragma unroll
        for (int reg = 0; reg < 4; ++reg) {
          const int row = mt * 16 + q * 4 + reg;
          redS[ng][row] = ps[mt][reg]; redS2[ng][row] = ps2[mt][reg];
        }
    }
  }
  __syncthreads();
  if (tid < MT) {
    const float s  = redS[0][tid] + redS[1][tid] + redS[2][tid] + redS[3][tid];
    const float s2 = redS2[0][tid] + redS2[1][tid] + redS2[2][tid] + redS2[3][tid];
    const float mu = s * (1.f / DD);
    const float var = s2 * (1.f / DD) - mu * mu;
    muL[tid] = mu; invL[tid] = rsqrtf(var + EPSLN);
  }
  __syncthreads();

  // ---- h (bf16) -> bufA rows 0..31 ----
  if (mg == 0) {
#pragma unroll
    for (int nt = 0; nt < 4; ++nt) {
      const int col = ng * 64 + nt * 16 + cl;
      const float gv = g1[col], bv = b1[col];
#pragma unroll
      for (int mt = 0; mt < 2; ++mt)
#pragma unroll
        for (int reg = 0; reg < 4; ++reg) {
          const int row = mt * 16 + q * 4 + reg;
          const float hv = (acc[mt][nt][reg] - muL[row]) * invL[row] * gv + bv;
          bufA[row * XPITCH + col] = f2bf(hv);
        }
    }
  }
  __syncthreads();

  // ============ FFN: 4 chunks of 256 H-cols; wave tile 32 x 32 ============
  u16* asb = (u16*)bufB;                           // 16.9 KB inside 33.3
  f32x4 acc2[2][2];
#pragma unroll
  for (int nt = 0; nt < 2; ++nt) {
    const float bv = bf2[wv * 32 + nt * 16 + cl];
#pragma unroll
    for (int mt = 0; mt < 2; ++mt) acc2[mt][nt] = (f32x4){bv, bv, bv, bv};
  }

  for (int c = 0; c < 4; ++c) {
    // FF1: rows 0..31 (mt) x chunk-cols [wv*32,+32), K = 256
    f32x4 acc1[2][2];
#pragma unroll
    for (int nt = 0; nt < 2; ++nt) {
      const float bv = bf1[c * 256 + wv * 32 + nt * 16 + cl];
#pragma unroll
      for (int mt = 0; mt < 2; ++mt) acc1[mt][nt] = (f32x4){bv, bv, bv, bv};
    }
#pragma unroll
    for (int s = 0; s < 8; ++s) {
      short8 a[2], b[2];
#pragma unroll
      for (int mt = 0; mt < 2; ++mt)
        a[mt] = *(const short8*)&bufA[(mt * 16 + cl) * XPITCH + s * 32 + q * 8];
      const u16* bp = w1pk + (size_t)(c * 8 + s) * 8192 + (size_t)(wv * 2) * 512 + (size_t)l * 8;
#pragma unroll
      for (int nt = 0; nt < 2; ++nt)
        b[nt] = *(const short8*)(bp + nt * 512);
#pragma unroll
      for (int mt = 0; mt < 2; ++mt)
#pragma unroll
        for (int nt = 0; nt < 2; ++nt)
          acc1[mt][nt] = MFMA(a[mt], b[nt], acc1[mt][nt]);
    }
    // exact gelu -> asb (A-layout, chunk-local cols wv*32+nt*16+cl)
#pragma unroll
    for (int mt = 0; mt < 2; ++mt)
#pragma unroll
      for (int nt = 0; nt < 2; ++nt)
#pragma unroll
        for (int reg = 0; reg < 4; ++reg) {
          const float v = acc1[mt][nt][reg];
          const float g = 0.5f * v * (1.f + erff(v * 0.70710678118654752f));
          asb[(mt * 16 + q * 4 + reg) * XPITCH + wv * 32 + nt * 16 + cl] = f2bf(g);
        }
    __syncthreads();
    // FF2: rows 0..31 x out-cols [wv*32,+32), K = chunk's 256
#pragma unroll
    for (int s = 0; s < 8; ++s) {
      short8 a[2], b[2];
#pragma unroll
      for (int mt = 0; mt < 2; ++mt)
        a[mt] = *(const short8*)&asb[(mt * 16 + cl) * XPITCH + s * 32 + q * 8];
      const u16* bp = w2pk + (size_t)(c * 8 + s) * 8192 + (size_t)(wv * 2) * 512 + (size_t)l * 8;
#pragma unroll
      for (int nt = 0; nt < 2; ++nt)
        b[nt] = *(const short8*)(bp + nt * 512);
#pragma unroll
      for (int mt = 0; mt < 2; ++mt)
#pragma unroll
        for (int nt = 0; nt < 2; ++nt)
          acc2[mt][nt] = MFMA(a[mt], b[nt], acc2[mt][nt]);
    }
    __syncthreads();                               // asb reused next chunk
  }

  // ---- residual (h from bufA) + LN2 ----
  {
    float ps[2][4], ps2[2][4];
#pragma unroll
    for (int mt = 0; mt < 2; ++mt)
#pragma unroll
      for (int reg = 0; reg < 4; ++reg) {
        const int row = mt * 16 + q * 4 + reg;
        float s = 0.f, s2 = 0.f;
#pragma unroll
        for (int nt = 0; nt < 2; ++nt) {
          const int col = wv * 32 + nt * 16 + cl;
          const float y = acc2[mt][nt][reg] + bf2f(bufA[row * XPITCH + col]);
          acc2[mt][nt][reg] = y;
          s += y; s2 += y * y;
        }
#pragma unroll
        for (int off = 1; off < 16; off <<= 1) { s += __shfl_xor(s, off, 64); s2 += __shfl_xor(s2, off, 64); }
        ps[mt][reg] = s; ps2[mt][reg] = s2;
      }
    if (cl == 0) {
#pragma unroll
      for (int mt = 0; mt < 2; ++mt)
#pragma unroll
        for (int reg = 0; reg < 4; ++reg) {
          const int row = mt * 16 + q * 4 + reg;
          redS[wv][row] = ps[mt][reg]; redS2[wv][row] = ps2[mt][reg];
        }
    }
  }
  __syncthreads();
  if (tid < MT) {
    float s = 0.f, s2 = 0.f;
#pragma unroll
    for (int k = 0; k < 8; ++k) { s += redS[k][tid]; s2 += redS2[k][tid]; }
    const float mu = s * (1.f / DD);
    const float var = s2 * (1.f / DD) - mu * mu;
    muL[tid] = mu; invL[tid] = rsqrtf(var + EPSLN);
  }
  __syncthreads();

#pragma unroll
  for (int nt = 0; nt < 2; ++nt) {
    const int col = wv * 32 + nt * 16 + cl;
    const float gv = g2[col], bv = b2[col];
#pragma unroll
    for (int mt = 0; mt < 2; ++mt)
#pragma unroll
      for (int reg = 0; reg < 4; ++reg) {
        const int row = mt * 16 + q * 4 + reg;
        out[(tok0 + row) * DD + col] = (acc2[mt][nt][reg] - muL[row]) * invL[row] * gv + bv;
      }
  }
}

// ---------------- launch ----------------
extern "C" void kernel_launch(void* const* d_in, const int* in_sizes, int n_in,
                              void* d_out, int out_size, void* d_ws, size_t ws_size,
                              hipStream_t stream) {
  const float* x    = (const float*)d_in[0];
  const float* wmix = (const float*)d_in[1];   // [3840][256]
  const float* bmix = (const float*)d_in[2];
  const float* g1   = (const float*)d_in[3];
  const float* b1   = (const float*)d_in[4];
  const float* wff1 = (const float*)d_in[5];   // [256][1024]
  const float* bff1 = (const float*)d_in[6];
  const float* wff2 = (const float*)d_in[7];   // [1024][256]
  const float* bff2 = (const float*)d_in[8];
  const float* g2   = (const float*)d_in[9];
  const float* b2   = (const float*)d_in[10];
  float* out = (float*)d_out;

  u16* wpk  = (u16*)d_ws;                // 120*8192 = 983040 elems (1.97 MB)
  u16* w1pk = wpk + 983040;              // 32*8192 = 262144
  u16* w2pk = w1pk + 262144;             // 262144

  k_prep<<<184, 256, 0, stream>>>(wmix, wff1, wff2, wpk, w1pk, w2pk);

  k_fused<<<512, 512, 0, stream>>>(x, wpk, bmix, g1, b1,
                                   w1pk, bff1, w2pk, bff2, g2, b2, out);
}